// Round 5
// baseline (77.268 us; speedup 1.0000x reference)
//
#include <hip/hip_runtime.h>
#include <math.h>

#define BB 32
#define SS 2048
#define HH 1024
#define RR 64
#define H4 (HH/4)
#define NPROD 16              // producer blocks per batch (each does 64 h-rows)
#define SPIN_CAP 200000

// flag: 0 = int32, 1 = uint8(bool), 2 = float32
__device__ __forceinline__ bool read_mask(const void* m, int flag, int i) {
    if (flag == 1) return ((const unsigned char*)m)[i] != 0;
    if (flag == 2) return ((const float*)m)[i] != 0.0f;
    return ((const int*)m)[i] != 0;
}

__device__ __forceinline__ float dot4(float4 a, float4 b) {
    return a.x * b.x + a.y * b.y + a.z * b.z + a.w * b.w;
}

// ---------------- mega kernel: pool + matvec + scores + softmax ------------
// grid = B*R = 2048, block = 256, blk = r*32 + b.
//   producers (r < 16): pool a[b] -> LDS, compute v[b, r*64 .. r*64+64),
//     publish via relaxed-agent stores + vmcnt(0) + device atomicAdd(vcnt[b]).
//   all blocks: pool rubric span u (bulk HBM phase, overlaps producers),
//     spin on vcnt[b]==16 (1 thread), dot u.v, fence-free softmax handoff.
// __launch_bounds__(256,8): VGPR<=64 -> 8 blocks/CU -> all 2048 co-resident
// (spin-safe). Bounded spin + W-direct fallback guarantees termination anyway.
__global__ __launch_bounds__(256, 8)
void mega_k(const float4* __restrict__ seq,
            const float4* __restrict__ W4,
            const int* __restrict__ rspan,
            const int* __restrict__ aspan,
            const void* __restrict__ mask,
            const float* __restrict__ bias,
            float* __restrict__ v,
            unsigned int* __restrict__ vcnt,
            unsigned int* __restrict__ cnt,
            float* __restrict__ scores,
            float* __restrict__ out) {
    int blk = blockIdx.x, t = threadIdx.x;
    int b = blk & (BB - 1);
    int r = blk >> 5;
    int idx = b * RR + r;
    int wave = t >> 6, lane = t & 63;

    // --- mask dtype classify (per block; 2048-B scan, L2-resident) ---
    // uint8 bool => nonzero at i%4==1; f32 => nonzero only at i%4==3;
    // int32 => nonzero only at i%4==0.
    __shared__ int c1s, c3s;
    if (t == 0) { c1s = 0; c3s = 0; }
    __syncthreads();
    {
        const unsigned char* mb = (const unsigned char*)mask;
        int c1 = 0, c3 = 0;
        for (int i = t; i < BB * RR; i += 256) {
            if (mb[i]) {
                int p = i & 3;
                if (p == 1) c1 = 1;
                else if (p == 3) c3 = 1;
            }
        }
        if (c1) atomicOr(&c1s, 1);
        if (c3) atomicOr(&c3s, 1);
    }
    __syncthreads();
    int flag = c1s ? 1 : (c3s ? 2 : 0);
    bool mk = read_mask(mask, flag, idx);

    __shared__ float4 aS[256];

    // ---------------- producer duty ----------------
    if (r < NPROD) {
        int s0 = aspan[2 * b], s1 = aspan[2 * b + 1];
        int alen = s1 - s0; if (alen < 1) alen = 1;
        float4 acc = make_float4(0.f, 0.f, 0.f, 0.f);
        const float4* base = seq + (size_t)b * SS * H4 + t;
        for (int s = s0; s < s1; ++s) {
            float4 x = base[(size_t)s * H4];
            acc.x += x.x; acc.y += x.y; acc.z += x.z; acc.w += x.w;
        }
        float inv = 1.0f / (float)alen;
        acc.x *= inv; acc.y *= inv; acc.z *= inv; acc.w *= inv;
        aS[t] = acc;
        __syncthreads();
        float4 al0 = aS[0 * 64 + lane];
        float4 al1 = aS[1 * 64 + lane];
        float4 al2 = aS[2 * 64 + lane];
        float4 al3 = aS[3 * 64 + lane];
        int hbase = r * 64 + wave * 16;
        for (int rr = 0; rr < 16; ++rr) {
            int h = hbase + rr;
            const float4* Wrow = W4 + (size_t)h * H4;
            float p = dot4(Wrow[0 * 64 + lane], al0)
                    + dot4(Wrow[1 * 64 + lane], al1)
                    + dot4(Wrow[2 * 64 + lane], al2)
                    + dot4(Wrow[3 * 64 + lane], al3);
            for (int off = 32; off; off >>= 1) p += __shfl_down(p, off);
            if (lane == 0)
                __hip_atomic_store(&v[b * HH + h], p, __ATOMIC_RELAXED,
                                   __HIP_MEMORY_SCOPE_AGENT);
        }
        asm volatile("s_waitcnt vmcnt(0)" ::: "memory"); // per-wave drain
        __syncthreads();                                 // all waves drained
        if (t == 0) atomicAdd(&vcnt[b], 1u);             // device-scope signal
    }

    // ---------------- rubric span pooling (bulk HBM, overlaps producers) ----
    float4 u = make_float4(0.f, 0.f, 0.f, 0.f);
    int rlen = 1;
    if (mk) {
        int s0 = rspan[idx * 2], s1 = rspan[idx * 2 + 1];
        rlen = s1 - s0; if (rlen < 1) rlen = 1;
        const float4* base = seq + (size_t)b * SS * H4 + t;
        for (int s = s0; s < s1; ++s) {
            float4 x = base[(size_t)s * H4];
            u.x += x.x; u.y += x.y; u.z += x.z; u.w += x.w;
        }
    }

    // ---------------- wait for v[b], then dot ----------------
    float p = 0.f;
    if (mk) {
        __shared__ int vready;
        if (t == 0) {
            unsigned c; int it = 0;
            do {
                c = __hip_atomic_load(&vcnt[b], __ATOMIC_RELAXED,
                                      __HIP_MEMORY_SCOPE_AGENT);
                ++it;
            } while (c < NPROD && it < SPIN_CAP);
            vready = (c >= NPROD);
        }
        __syncthreads();
        if (vready) {
            float v0 = __hip_atomic_load(&v[b * HH + 4 * t + 0], __ATOMIC_RELAXED,
                                         __HIP_MEMORY_SCOPE_AGENT);
            float v1 = __hip_atomic_load(&v[b * HH + 4 * t + 1], __ATOMIC_RELAXED,
                                         __HIP_MEMORY_SCOPE_AGENT);
            float v2 = __hip_atomic_load(&v[b * HH + 4 * t + 2], __ATOMIC_RELAXED,
                                         __HIP_MEMORY_SCOPE_AGENT);
            float v3 = __hip_atomic_load(&v[b * HH + 4 * t + 3], __ATOMIC_RELAXED,
                                         __HIP_MEMORY_SCOPE_AGENT);
            p = u.x * v0 + u.y * v1 + u.z * v2 + u.w * v3;
        } else {
            // fallback (never in practice): recompute v[4t..4t+3] from W, a.
            int s0 = aspan[2 * b], s1 = aspan[2 * b + 1];
            int alen = s1 - s0; if (alen < 1) alen = 1;
            float4 acc = make_float4(0.f, 0.f, 0.f, 0.f);
            const float4* base = seq + (size_t)b * SS * H4 + t;
            for (int s = s0; s < s1; ++s) {
                float4 x = base[(size_t)s * H4];
                acc.x += x.x; acc.y += x.y; acc.z += x.z; acc.w += x.w;
            }
            float inv = 1.0f / (float)alen;
            acc.x *= inv; acc.y *= inv; acc.z *= inv; acc.w *= inv;
            __syncthreads();
            aS[t] = acc;
            __syncthreads();
            float uu[4] = {u.x, u.y, u.z, u.w};
            for (int j = 0; j < 4; ++j) {
                int h = 4 * t + j;
                const float4* Wrow = W4 + (size_t)h * H4;
                float s = 0.f;
                for (int k = 0; k < H4; ++k) s += dot4(Wrow[k], aS[k]);
                p += uu[j] * s;
            }
        }
    }

    // ---------------- block reduce + fence-free softmax handoff -------------
    __shared__ float red[4];
    __shared__ int lastB;
    for (int off = 32; off; off >>= 1) p += __shfl_down(p, off);
    if (lane == 0) red[wave] = p;
    __syncthreads();
    if (t == 0) {
        float s = red[0] + red[1] + red[2] + red[3];
        float val = mk ? (s / (float)rlen + bias[0]) : -INFINITY;
        __hip_atomic_store(&scores[idx], val, __ATOMIC_RELAXED,
                           __HIP_MEMORY_SCOPE_AGENT);
        asm volatile("s_waitcnt vmcnt(0)" ::: "memory"); // score @ coherence pt
        unsigned old = atomicAdd(&cnt[b], 1u);           // relaxed, device
        asm volatile("" ::: "memory");
        lastB = (old == RR - 1);
    }
    __syncthreads();
    if (lastB && t < RR) {
        float x = __hip_atomic_load(&scores[b * RR + t], __ATOMIC_RELAXED,
                                    __HIP_MEMORY_SCOPE_AGENT);
        float m = x;
        for (int off = 32; off; off >>= 1) m = fmaxf(m, __shfl_xor(m, off));
        float e = expf(x - m);              // -inf lanes -> 0
        float s = e;
        for (int off = 32; off; off >>= 1) s += __shfl_xor(s, off);
        out[b * RR + t] = e / s;
    }
}

extern "C" void kernel_launch(void* const* d_in, const int* in_sizes, int n_in,
                              void* d_out, int out_size, void* d_ws, size_t ws_size,
                              hipStream_t stream) {
    const float* seq  = (const float*)d_in[0];
    const float* Wm   = (const float*)d_in[1];
    const float* bias = (const float*)d_in[2];
    const int*   rspan = (const int*)d_in[3];
    const int*   aspan = (const int*)d_in[4];
    const void*  mask  = d_in[5];

    char* ws = (char*)d_ws;
    unsigned int* cnt    = (unsigned int*)ws;               // 32 u32
    unsigned int* vcnt   = (unsigned int*)(ws + 128);       // 32 u32
    float*        scores = (float*)(ws + 4096);             // 2048 f
    float*        v      = (float*)(ws + 16384);            // 32*1024 f

    hipMemsetAsync(ws, 0, 256, stream);                     // zero cnt+vcnt
    mega_k<<<BB * RR, 256, 0, stream>>>(
        (const float4*)seq, (const float4*)Wm, rspan, aspan, mask, bias,
        v, vcnt, cnt, scores, (float*)d_out);
}

// Round 6
// 41.679 us; speedup vs baseline: 1.8539x; 1.8539x over previous
//
#include <hip/hip_runtime.h>
#include <math.h>

#define BB 32
#define SS 2048
#define HH 1024
#define RR 64
#define H4 (HH/4)

// flag: 0 = int32, 1 = uint8(bool), 2 = float32
__device__ __forceinline__ bool read_mask(const void* m, int flag, int i) {
    if (flag == 1) return ((const unsigned char*)m)[i] != 0;
    if (flag == 2) return ((const float*)m)[i] != 0.0f;
    return ((const int*)m)[i] != 0;
}

__device__ __forceinline__ float dot4(float4 a, float4 b) {
    return a.x * b.x + a.y * b.y + a.z * b.z + a.w * b.w;
}

// ---------------- K1: answer pool + bilinear matvec (fused) ----------------
// grid = 512, block = 256. b = blk&31, hg = blk>>5  (XCD swizzle: all 16
// blocks of batch b land on XCD b%8, so the ~124 KB of answer rows is
// fetched once into that XCD's L2 and the other 15 blocks hit L2 — R4 had
// b=blk>>4 which scattered them across all 8 XCDs, ~63 MB of raw L3 traffic).
// Each block recomputes a[b], stashes it in LDS, then computes
// v[b, hg*64 .. hg*64+64) with coalesced W reads.
// Block 0 additionally classifies the rubric_mask storage dtype and zeroes
// the per-batch completion counters used by K2's fused softmax.
__global__ void pool_matvec_k(const float4* __restrict__ seq,
                              const float4* __restrict__ W4,
                              const int* __restrict__ aspan,
                              const unsigned char* __restrict__ mask,
                              float* __restrict__ v,
                              int* __restrict__ flag,
                              unsigned int* __restrict__ cnt) {
    int blk = blockIdx.x, t = threadIdx.x;
    int b = blk & (BB - 1), hg = blk >> 5;

    // --- answer span mean pooling (thread t owns float4 chunk t of H) ---
    int s0 = aspan[2 * b], s1 = aspan[2 * b + 1];
    int len = s1 - s0; if (len < 1) len = 1;
    float4 acc = make_float4(0.f, 0.f, 0.f, 0.f);
    const float4* base = seq + (size_t)b * SS * H4 + t;
    for (int s = s0; s < s1; ++s) {
        float4 x = base[(size_t)s * H4];
        acc.x += x.x; acc.y += x.y; acc.z += x.z; acc.w += x.w;
    }
    float inv = 1.0f / (float)len;
    acc.x *= inv; acc.y *= inv; acc.z *= inv; acc.w *= inv;

    __shared__ float4 aS[256];
    aS[t] = acc;
    __syncthreads();

    // --- matvec: wave w handles rows hg*64 + w*16 .. +16 ---
    int wave = t >> 6, lane = t & 63;
    // lane's a-slice: elements (k*64+lane)*4 .. +4, k = 0..3
    float4 al0 = aS[0 * 64 + lane];
    float4 al1 = aS[1 * 64 + lane];
    float4 al2 = aS[2 * 64 + lane];
    float4 al3 = aS[3 * 64 + lane];
    int hbase = hg * 64 + wave * 16;
    for (int r = 0; r < 16; ++r) {
        int h = hbase + r;
        const float4* Wrow = W4 + (size_t)h * H4;
        // coalesced: consecutive lanes -> consecutive float4s
        float p = dot4(Wrow[0 * 64 + lane], al0)
                + dot4(Wrow[1 * 64 + lane], al1)
                + dot4(Wrow[2 * 64 + lane], al2)
                + dot4(Wrow[3 * 64 + lane], al3);
        for (int off = 32; off; off >>= 1) p += __shfl_down(p, off);
        if (lane == 0) v[b * HH + h] = p;
    }

    // --- block 0 side duties: mask dtype classify + counter zero ---
    if (blk == 0) {
        __shared__ int c1s, c3s;
        if (t == 0) { c1s = 0; c3s = 0; }
        __syncthreads();
        int c1 = 0, c3 = 0;
        for (int i = t; i < BB * RR; i += 256) {
            if (mask[i]) {
                int p = i & 3;
                if (p == 1) c1 = 1;
                else if (p == 3) c3 = 1;
            }
        }
        if (c1) atomicOr(&c1s, 1);
        if (c3) atomicOr(&c3s, 1);
        __syncthreads();
        if (t == 0) *flag = c1s ? 1 : (c3s ? 2 : 0);
        if (t < BB) cnt[t] = 0u;    // re-zero every launch (graph replay safe)
    }
}

// ---------------- K2: rubric scores + fused softmax ----------------
// grid = B*R, block = 256. blk = r*32 + b so batch b's 64 blocks land on XCD
// b%8 (span-row L2 reuse). Fence-free cross-XCD handoff (R3-proven): relaxed
// agent-scope (sc1) score stores/loads ordered by s_waitcnt vmcnt(0) before a
// relaxed device-scope counter bump. No acquire/release -> no L2 cache walks
// (R2's acq_rel version cost ~160 us in serialized cache maintenance).
__global__ void rubric_scores_softmax_k(const float4* __restrict__ seq,
                                        const float4* __restrict__ v4,
                                        const int* __restrict__ rspan,
                                        const void* __restrict__ mask,
                                        const int* __restrict__ flagp,
                                        const float* __restrict__ bias,
                                        float* __restrict__ scores,
                                        unsigned int* __restrict__ cnt,
                                        float* __restrict__ out) {
    int blk = blockIdx.x;
    int b = blk & (BB - 1);
    int r = blk >> 5;
    int t = threadIdx.x;
    int idx = b * RR + r;
    int flag = *flagp;
    bool mk = read_mask(mask, flag, idx);

    float p = 0.f;
    int len = 1;
    if (mk) {
        int s0 = rspan[idx * 2], s1 = rspan[idx * 2 + 1];
        len = s1 - s0; if (len < 1) len = 1;
        float4 vv = v4[b * H4 + t];
        const float4* base = seq + (size_t)b * SS * H4 + t;
        for (int s = s0; s < s1; ++s) {
            float4 x = base[(size_t)s * H4];
            p += x.x * vv.x + x.y * vv.y + x.z * vv.z + x.w * vv.w;
        }
    }
    __shared__ float red[4];
    __shared__ int lastB;
    int wave = t >> 6, lane = t & 63;
    for (int off = 32; off; off >>= 1) p += __shfl_down(p, off);
    if (lane == 0) red[wave] = p;
    __syncthreads();
    if (t == 0) {
        float s = red[0] + red[1] + red[2] + red[3];
        float val = mk ? (s / (float)len + bias[0]) : -INFINITY;
        __hip_atomic_store(&scores[idx], val, __ATOMIC_RELAXED,
                           __HIP_MEMORY_SCOPE_AGENT);
        asm volatile("s_waitcnt vmcnt(0)" ::: "memory");  // score @ coherence pt
        unsigned old = atomicAdd(&cnt[b], 1u);            // relaxed, device
        asm volatile("" ::: "memory");
        lastB = (old == RR - 1);
    }
    __syncthreads();
    if (lastB && t < RR) {
        float x = __hip_atomic_load(&scores[b * RR + t], __ATOMIC_RELAXED,
                                    __HIP_MEMORY_SCOPE_AGENT);
        float m = x;
        for (int off = 32; off; off >>= 1) m = fmaxf(m, __shfl_xor(m, off));
        float e = expf(x - m);              // -inf lanes -> 0
        float s = e;
        for (int off = 32; off; off >>= 1) s += __shfl_xor(s, off);
        out[b * RR + t] = e / s;
    }
}

extern "C" void kernel_launch(void* const* d_in, const int* in_sizes, int n_in,
                              void* d_out, int out_size, void* d_ws, size_t ws_size,
                              hipStream_t stream) {
    const float* seq  = (const float*)d_in[0];
    const float* Wm   = (const float*)d_in[1];
    const float* bias = (const float*)d_in[2];
    const int*   rspan = (const int*)d_in[3];
    const int*   aspan = (const int*)d_in[4];
    const void*  mask  = d_in[5];

    char* ws = (char*)d_ws;
    int*          flag   = (int*)ws;                        // @0
    unsigned int* cnt    = (unsigned int*)(ws + 256);       // 32 u32
    float*        scores = (float*)(ws + 4096);             // 2048 f
    float*        v      = (float*)(ws + 16384);            // 32*1024 f

    pool_matvec_k<<<BB * 16, 256, 0, stream>>>(
        (const float4*)seq, (const float4*)Wm, aspan,
        (const unsigned char*)mask, v, flag, cnt);
    rubric_scores_softmax_k<<<BB * RR, 256, 0, stream>>>(
        (const float4*)seq, (const float4*)v, rspan, mask, flag, bias,
        scores, cnt, (float*)d_out);
}